// Round 4
// baseline (240.094 us; speedup 1.0000x reference)
//
#include <hip/hip_runtime.h>
#include <hip/hip_fp16.h>
#include <cstdint>

#define IN_U 2048
#define OUT_U 2048
#define NH 10
#define BATCH 4096

typedef _Float16 f16;
typedef _Float16 f16x8 __attribute__((ext_vector_type(8)));
typedef float f32x4 __attribute__((ext_vector_type(4)));
typedef float f32x16 __attribute__((ext_vector_type(16)));

// ================= k_prep: fused rowA | colB-partials | castX =================
__global__ __launch_bounds__(256) void k_prep(const float* __restrict__ W,
                                              const float* __restrict__ W1,
                                              const float* __restrict__ X,
                                              float* __restrict__ A,
                                              float* __restrict__ Bp,
                                              f16* __restrict__ X16) {
  __shared__ float red[4 * 64 * NH];
  int blk = blockIdx.x;
  int tid = threadIdx.x;
  int lane = tid & 63;
  int wv = tid >> 6;

  if (blk < 512) {
    // ---- rowA: A[i][h] = sum_k W[i][k]*W1[k][h]; i = blk*4 + wv ----
    int i = blk * 4 + wv;
    float acc[NH];
#pragma unroll
    for (int h = 0; h < NH; ++h) acc[h] = 0.f;
    const float* wrow = W + (size_t)i * OUT_U;
    for (int k0 = lane * 4; k0 < OUT_U; k0 += 256) {
      float4 w4 = *(const float4*)(wrow + k0);
#pragma unroll
      for (int e = 0; e < 4; ++e) {
        float wval = (&w4.x)[e];
        const float2* w1p = (const float2*)(W1 + (size_t)(k0 + e) * NH);  // 8B-aligned (k*40)
        float2 p0 = w1p[0], p1 = w1p[1], p2 = w1p[2], p3 = w1p[3], p4 = w1p[4];
        acc[0] = fmaf(wval, p0.x, acc[0]); acc[1] = fmaf(wval, p0.y, acc[1]);
        acc[2] = fmaf(wval, p1.x, acc[2]); acc[3] = fmaf(wval, p1.y, acc[3]);
        acc[4] = fmaf(wval, p2.x, acc[4]); acc[5] = fmaf(wval, p2.y, acc[5]);
        acc[6] = fmaf(wval, p3.x, acc[6]); acc[7] = fmaf(wval, p3.y, acc[7]);
        acc[8] = fmaf(wval, p4.x, acc[8]); acc[9] = fmaf(wval, p4.y, acc[9]);
      }
    }
#pragma unroll
    for (int off = 32; off > 0; off >>= 1) {
#pragma unroll
      for (int h = 0; h < NH; ++h) acc[h] += __shfl_xor(acc[h], off, 64);
    }
    if (lane == 0) {
#pragma unroll
      for (int h = 0; h < NH; ++h) A[(size_t)i * NH + h] = acc[h];
    }
  } else if (blk < 768) {
    // ---- colB partial: Bp[kc][j][h] = sum_{k in chunk kc} W[k][j]*W1b[k][h] ----
    int pb = blk - 512;
    int jt = pb & 31, kc = pb >> 5;
    int j = jt * 64 + lane;
    float acc[NH];
#pragma unroll
    for (int h = 0; h < NH; ++h) acc[h] = 0.f;
    const float* w1b = W1 + (size_t)OUT_U * NH;
    int k0 = kc * 256 + wv * 64;
#pragma unroll 4
    for (int k = k0; k < k0 + 64; ++k) {
      float wval = W[(size_t)k * OUT_U + j];
      const float2* w1p = (const float2*)(w1b + (size_t)k * NH);
      float2 p0 = w1p[0], p1 = w1p[1], p2 = w1p[2], p3 = w1p[3], p4 = w1p[4];
      acc[0] = fmaf(wval, p0.x, acc[0]); acc[1] = fmaf(wval, p0.y, acc[1]);
      acc[2] = fmaf(wval, p1.x, acc[2]); acc[3] = fmaf(wval, p1.y, acc[3]);
      acc[4] = fmaf(wval, p2.x, acc[4]); acc[5] = fmaf(wval, p2.y, acc[5]);
      acc[6] = fmaf(wval, p3.x, acc[6]); acc[7] = fmaf(wval, p3.y, acc[7]);
      acc[8] = fmaf(wval, p4.x, acc[8]); acc[9] = fmaf(wval, p4.y, acc[9]);
    }
#pragma unroll
    for (int h = 0; h < NH; ++h) red[wv * 640 + lane * NH + h] = acc[h];
    __syncthreads();
    for (int v = tid; v < 640; v += 256) {
      float s = red[v] + red[640 + v] + red[1280 + v] + red[1920 + v];
      Bp[(size_t)kc * (OUT_U * NH) + jt * 640 + v] = s;
    }
  } else {
    // ---- castX ----
    int idx = (blk - 768) * 256 + tid;
    const float4* src = (const float4*)X;
    float4 a = src[idx * 2];
    float4 b = src[idx * 2 + 1];
    f16x8 o;
    o[0] = (f16)a.x; o[1] = (f16)a.y; o[2] = (f16)a.z; o[3] = (f16)a.w;
    o[4] = (f16)b.x; o[5] = (f16)b.y; o[6] = (f16)b.z; o[7] = (f16)b.w;
    *((f16x8*)X16 + idx) = o;
  }
}

// ================= k_wnew: W_new^T (f16), B-partials reduced in =================
__global__ __launch_bounds__(256) void k_wnew(const float* __restrict__ W,
                                              const float* __restrict__ A,
                                              const float* __restrict__ Bp,
                                              const float* __restrict__ b1,
                                              const float* __restrict__ W2,
                                              const float* __restrict__ b2,
                                              const float* __restrict__ W3,
                                              const float* __restrict__ b3,
                                              f16* __restrict__ WnT) {
  __shared__ float Wt[64 * 65];
  __shared__ float As[64 * NH];
  __shared__ float Bs[64 * NH];
  __shared__ float W2s[NH * NH];
  __shared__ float b1s[NH], b2s[NH], w3s[NH];
  int tid = threadIdx.x;
  int i0 = blockIdx.x * 64, j0 = blockIdx.y * 64;
#pragma unroll
  for (int it = 0; it < 16; ++it) {
    int idx = it * 256 + tid;
    int r = idx >> 6, c = idx & 63;
    Wt[c * 65 + r] = W[(size_t)(i0 + r) * OUT_U + j0 + c];
  }
  for (int v = tid; v < 64 * NH; v += 256) {
    As[v] = A[(size_t)i0 * NH + v];
    float s = 0.f;
#pragma unroll
    for (int kc = 0; kc < 8; ++kc) s += Bp[(size_t)kc * (OUT_U * NH) + (size_t)j0 * NH + v];
    Bs[v] = s;
  }
  if (tid < NH * NH) W2s[tid] = W2[tid];
  if (tid < NH) { b1s[tid] = b1[tid]; b2s[tid] = b2[tid]; w3s[tid] = W3[tid]; }
  __syncthreads();

  int lane = tid & 63, w = tid >> 6;
  float b3v = b3[0];
  float ar[NH];
#pragma unroll
  for (int h = 0; h < NH; ++h) ar[h] = As[lane * NH + h] + b1s[h];

#pragma unroll 1
  for (int g = 0; g < 4; ++g) {
    int jb = w * 16 + g * 4;  // wave-uniform
    float h1[4][NH], s2[4][NH];
#pragma unroll
    for (int u = 0; u < 4; ++u)
#pragma unroll
      for (int p = 0; p < NH; ++p)
        h1[u][p] = fmaxf(ar[p] + Bs[(jb + u) * NH + p], 0.f);
#pragma unroll
    for (int u = 0; u < 4; ++u)
#pragma unroll
      for (int q = 0; q < NH; ++q) s2[u][q] = b2s[q];
#pragma unroll
    for (int p = 0; p < NH; ++p) {
#pragma unroll
      for (int q = 0; q < NH; ++q) {
        float wv2 = W2s[p * NH + q];  // wave-uniform broadcast, conflict-free
#pragma unroll
        for (int u = 0; u < 4; ++u) s2[u][q] = fmaf(h1[u][p], wv2, s2[u][q]);
      }
    }
#pragma unroll
    for (int u = 0; u < 4; ++u) {
      float d = b3v;
#pragma unroll
      for (int q = 0; q < NH; ++q) d = fmaf(fmaxf(s2[u][q], 0.f), w3s[q], d);
      float wn = Wt[(jb + u) * 65 + lane] + d;
      WnT[(size_t)(j0 + jb + u) * IN_U + i0 + lane] = (f16)wn;
    }
  }
}

// ================= k_gemm: logits = X16 @ WnT^T =================
// 128x128 tile, BK=64, single-buffered; 32x32x16 MFMA; T2 both-sides XOR swizzle
// (linear gld_lds dest + inverse-swizzled GLOBAL source + swizzled ds_read, rule #21);
// T1 bijective XCD swizzle (512 blocks % 8 == 0).
__device__ __forceinline__ void gld_lds16(const void* g, void* l) {
  __builtin_amdgcn_global_load_lds((const __attribute__((address_space(1))) uint32_t*)g,
                                   (__attribute__((address_space(3))) uint32_t*)l, 16, 0, 0);
}

__global__ __launch_bounds__(256) void k_gemm(const f16* __restrict__ Am,
                                              const f16* __restrict__ Bt,
                                              float* __restrict__ C) {
  constexpr int K = IN_U;    // 2048
  constexpr int N = OUT_U;   // 2048
  constexpr int BK = 64;
  constexpr int NKT = K / BK;  // 32
  __shared__ f16 Asl[128 * BK];  // 16 KB, logical [row][chunk^(row&7)] physical-linear
  __shared__ f16 Bsl[128 * BK];  // 16 KB
  int tid = threadIdx.x;
  int lane = tid & 63;
  int w = tid >> 6;
  int wr = w >> 1, wc = w & 1;

  int orig = blockIdx.x;
  int swz = (orig & 7) * 64 + (orig >> 3);
  int bm = swz >> 4;   // 0..31
  int bn = swz & 15;   // 0..15

  // staging: each instr covers 8 rows x 64 f16 (1 KB); 4 instrs/wave/matrix.
  // dest is linear (lane*16B); source column chunk pre-swizzled by row&7.
  int srow = lane >> 3;                    // 0..7, == row&7 (row = w*32 + i*8 + srow)
  int schunk = (lane & 7) ^ srow;          // inverse swizzle on global source
  const f16* sA = Am + (size_t)(bm * 128 + w * 32 + srow) * K + schunk * 8;
  const f16* sB = Bt + (size_t)(bn * 128 + w * 32 + srow) * K + schunk * 8;
  f16* dA = Asl + w * 32 * BK;
  f16* dB = Bsl + w * 32 * BK;

  f32x16 acc[2][2];
#pragma unroll
  for (int mi = 0; mi < 2; ++mi)
#pragma unroll
    for (int ni = 0; ni < 2; ++ni) acc[mi][ni] = (f32x16)(0.f);

  // ds_read: A row = wr*64 + mi*32 + (lane&31); chunk = ks*2 + (lane>>5); phys = chunk^(row&7)
  int arow = wr * 64 + (lane & 31);
  int brow = wc * 64 + (lane & 31);
  int kgrp = lane >> 5;    // 0/1
  int rswz = lane & 7;     // == row&7 for both operands (offsets are multiples of 32)

  for (int kt = 0; kt < NKT; ++kt) {
#pragma unroll
    for (int i = 0; i < 4; ++i) {
      gld_lds16(sA + (size_t)i * 8 * K, dA + i * 8 * BK);
      gld_lds16(sB + (size_t)i * 8 * K, dB + i * 8 * BK);
    }
    sA += BK; sB += BK;
    __syncthreads();  // drains vmcnt(0): staged tile valid for all waves

    f16x8 af[2][4], bf[2][4];
#pragma unroll
    for (int mi = 0; mi < 2; ++mi)
#pragma unroll
      for (int ks = 0; ks < 4; ++ks) {
        int pc = (ks * 2 + kgrp) ^ rswz;
        af[mi][ks] = *(const f16x8*)(Asl + (size_t)(arow + mi * 32) * BK + pc * 8);
        bf[mi][ks] = *(const f16x8*)(Bsl + (size_t)(brow + mi * 32) * BK + pc * 8);
      }
#pragma unroll
    for (int ks = 0; ks < 4; ++ks)
#pragma unroll
      for (int mi = 0; mi < 2; ++mi)
#pragma unroll
        for (int ni = 0; ni < 2; ++ni)
          acc[mi][ni] = __builtin_amdgcn_mfma_f32_32x32x16_f16(af[mi][ks], bf[ni][ks], acc[mi][ni], 0, 0, 0);
    __syncthreads();  // all waves done reading before next-tile overwrite
  }

  // 32x32 C/D layout (m74/m101): col = lane&31, row = (v&3) + 8*(v>>2) + 4*(lane>>5)
  int c0 = bn * 128 + wc * 64 + (lane & 31);
  int r0 = bm * 128 + wr * 64 + (lane >> 5) * 4;
#pragma unroll
  for (int mi = 0; mi < 2; ++mi)
#pragma unroll
    for (int ni = 0; ni < 2; ++ni)
#pragma unroll
      for (int v = 0; v < 16; ++v) {
        int row = r0 + mi * 32 + (v & 3) + 8 * (v >> 2);
        C[(size_t)row * N + c0 + ni * 32] = acc[mi][ni][v];
      }
}

// ================= k_softmax: row softmax in-place =================
__global__ __launch_bounds__(256) void k_softmax(float* __restrict__ L) {
  __shared__ float sred[4];
  int tid = threadIdx.x;
  int lane = tid & 63, w = tid >> 6;
  float4* Lr = (float4*)(L + (size_t)blockIdx.x * OUT_U);
  float4 v0 = Lr[tid];
  float4 v1 = Lr[tid + 256];
  float m = fmaxf(fmaxf(fmaxf(v0.x, v0.y), fmaxf(v0.z, v0.w)),
                  fmaxf(fmaxf(v1.x, v1.y), fmaxf(v1.z, v1.w)));
#pragma unroll
  for (int off = 32; off > 0; off >>= 1) m = fmaxf(m, __shfl_xor(m, off, 64));
  if (lane == 0) sred[w] = m;
  __syncthreads();
  m = fmaxf(fmaxf(sred[0], sred[1]), fmaxf(sred[2], sred[3]));
  __syncthreads();
  v0.x = __expf(v0.x - m); v0.y = __expf(v0.y - m);
  v0.z = __expf(v0.z - m); v0.w = __expf(v0.w - m);
  v1.x = __expf(v1.x - m); v1.y = __expf(v1.y - m);
  v1.z = __expf(v1.z - m); v1.w = __expf(v1.w - m);
  float s = v0.x + v0.y + v0.z + v0.w + v1.x + v1.y + v1.z + v1.w;
#pragma unroll
  for (int off = 32; off > 0; off >>= 1) s += __shfl_xor(s, off, 64);
  if (lane == 0) sred[w] = s;
  __syncthreads();
  s = sred[0] + sred[1] + sred[2] + sred[3];
  float inv = 1.f / s;
  v0.x *= inv; v0.y *= inv; v0.z *= inv; v0.w *= inv;
  v1.x *= inv; v1.y *= inv; v1.z *= inv; v1.w *= inv;
  Lr[tid] = v0;
  Lr[tid + 256] = v1;
}

extern "C" void kernel_launch(void* const* d_in, const int* in_sizes, int n_in,
                              void* d_out, int out_size, void* d_ws, size_t ws_size,
                              hipStream_t stream) {
  const float* X  = (const float*)d_in[0];
  const float* W  = (const float*)d_in[1];
  const float* W1 = (const float*)d_in[2];
  const float* b1 = (const float*)d_in[3];
  const float* W2 = (const float*)d_in[4];
  const float* b2 = (const float*)d_in[5];
  const float* W3 = (const float*)d_in[6];
  const float* b3 = (const float*)d_in[7];
  float* out = (float*)d_out;

  uint8_t* ws = (uint8_t*)d_ws;
  float* A   = (float*)ws;                      // 81,920 B
  float* Bp  = (float*)(ws + 81920);            // 655,360 B
  f16*   X16 = (f16*)(ws + 737280);             // 16,777,216 B
  f16*   WnT = (f16*)(ws + 737280 + 16777216);  // 8,388,608 B

  hipLaunchKernelGGL(k_prep, dim3(4864), dim3(256), 0, stream, W, W1, X, A, Bp, X16);
  hipLaunchKernelGGL(k_wnew, dim3(32, 32), dim3(256), 0, stream, W, A, Bp, b1, W2, b2, W3, b3, WnT);
  hipLaunchKernelGGL(k_gemm, dim3(512), dim3(256), 0, stream, X16, WnT, out);
  hipLaunchKernelGGL(k_softmax, dim3(4096), dim3(256), 0, stream, out);
}

// Round 5
// 228.643 us; speedup vs baseline: 1.0501x; 1.0501x over previous
//
#include <hip/hip_runtime.h>
#include <hip/hip_fp16.h>
#include <cstdint>

#define IN_U 2048
#define OUT_U 2048
#define NH 10
#define BATCH 4096

typedef _Float16 f16;
typedef _Float16 f16x8 __attribute__((ext_vector_type(8)));
typedef float f32x4 __attribute__((ext_vector_type(4)));
typedef float f32x16 __attribute__((ext_vector_type(16)));

// ================= k_prep: fused rowA | colB-partials | castX =================
__global__ __launch_bounds__(256) void k_prep(const float* __restrict__ W,
                                              const float* __restrict__ W1,
                                              const float* __restrict__ X,
                                              float* __restrict__ A,
                                              float* __restrict__ Bp,
                                              f16* __restrict__ X16) {
  __shared__ float red[4 * 64 * NH];
  int blk = blockIdx.x;
  int tid = threadIdx.x;
  int lane = tid & 63;
  int wv = tid >> 6;

  if (blk < 512) {
    // ---- rowA: A[i][h] = sum_k W[i][k]*W1[k][h]; i = blk*4 + wv ----
    int i = blk * 4 + wv;
    float acc[NH];
#pragma unroll
    for (int h = 0; h < NH; ++h) acc[h] = 0.f;
    const float* wrow = W + (size_t)i * OUT_U;
    for (int k0 = lane * 4; k0 < OUT_U; k0 += 256) {
      float4 w4 = *(const float4*)(wrow + k0);
#pragma unroll
      for (int e = 0; e < 4; ++e) {
        float wval = (&w4.x)[e];
        const float2* w1p = (const float2*)(W1 + (size_t)(k0 + e) * NH);  // 8B-aligned (k*40)
        float2 p0 = w1p[0], p1 = w1p[1], p2 = w1p[2], p3 = w1p[3], p4 = w1p[4];
        acc[0] = fmaf(wval, p0.x, acc[0]); acc[1] = fmaf(wval, p0.y, acc[1]);
        acc[2] = fmaf(wval, p1.x, acc[2]); acc[3] = fmaf(wval, p1.y, acc[3]);
        acc[4] = fmaf(wval, p2.x, acc[4]); acc[5] = fmaf(wval, p2.y, acc[5]);
        acc[6] = fmaf(wval, p3.x, acc[6]); acc[7] = fmaf(wval, p3.y, acc[7]);
        acc[8] = fmaf(wval, p4.x, acc[8]); acc[9] = fmaf(wval, p4.y, acc[9]);
      }
    }
#pragma unroll
    for (int off = 32; off > 0; off >>= 1) {
#pragma unroll
      for (int h = 0; h < NH; ++h) acc[h] += __shfl_xor(acc[h], off, 64);
    }
    if (lane == 0) {
#pragma unroll
      for (int h = 0; h < NH; ++h) A[(size_t)i * NH + h] = acc[h];
    }
  } else if (blk < 768) {
    // ---- colB partial: Bp[kc][j][h] = sum_{k in chunk kc} W[k][j]*W1b[k][h] ----
    int pb = blk - 512;
    int jt = pb & 31, kc = pb >> 5;
    int j = jt * 64 + lane;
    float acc[NH];
#pragma unroll
    for (int h = 0; h < NH; ++h) acc[h] = 0.f;
    const float* w1b = W1 + (size_t)OUT_U * NH;
    int k0 = kc * 256 + wv * 64;
#pragma unroll 4
    for (int k = k0; k < k0 + 64; ++k) {
      float wval = W[(size_t)k * OUT_U + j];
      const float2* w1p = (const float2*)(w1b + (size_t)k * NH);
      float2 p0 = w1p[0], p1 = w1p[1], p2 = w1p[2], p3 = w1p[3], p4 = w1p[4];
      acc[0] = fmaf(wval, p0.x, acc[0]); acc[1] = fmaf(wval, p0.y, acc[1]);
      acc[2] = fmaf(wval, p1.x, acc[2]); acc[3] = fmaf(wval, p1.y, acc[3]);
      acc[4] = fmaf(wval, p2.x, acc[4]); acc[5] = fmaf(wval, p2.y, acc[5]);
      acc[6] = fmaf(wval, p3.x, acc[6]); acc[7] = fmaf(wval, p3.y, acc[7]);
      acc[8] = fmaf(wval, p4.x, acc[8]); acc[9] = fmaf(wval, p4.y, acc[9]);
    }
#pragma unroll
    for (int h = 0; h < NH; ++h) red[wv * 640 + lane * NH + h] = acc[h];
    __syncthreads();
    for (int v = tid; v < 640; v += 256) {
      float s = red[v] + red[640 + v] + red[1280 + v] + red[1920 + v];
      Bp[(size_t)kc * (OUT_U * NH) + jt * 640 + v] = s;
    }
  } else {
    // ---- castX ----
    int idx = (blk - 768) * 256 + tid;
    const float4* src = (const float4*)X;
    float4 a = src[idx * 2];
    float4 b = src[idx * 2 + 1];
    f16x8 o;
    o[0] = (f16)a.x; o[1] = (f16)a.y; o[2] = (f16)a.z; o[3] = (f16)a.w;
    o[4] = (f16)b.x; o[5] = (f16)b.y; o[6] = (f16)b.z; o[7] = (f16)b.w;
    *((f16x8*)X16 + idx) = o;
  }
}

// ================= k_wnew v3: W_new^T (f16) =================
// FULL unroll (R3's `unroll 1` caused 256-VGPR scratch spill: WRITE_SIZE 98MB,
// 78us). JB=4 j-blocking, float2 LDS broadcast reads, launch_bounds(256,2).
__global__ __launch_bounds__(256, 2) void k_wnew(const float* __restrict__ W,
                                                 const float* __restrict__ A,
                                                 const float* __restrict__ Bp,
                                                 const float* __restrict__ b1,
                                                 const float* __restrict__ W2,
                                                 const float* __restrict__ b2,
                                                 const float* __restrict__ W3,
                                                 const float* __restrict__ b3,
                                                 f16* __restrict__ WnT) {
  __shared__ float Wt[64 * 65];
  __shared__ float As[64 * NH];
  __shared__ float Bs[64 * NH];
  __shared__ float W2s[NH * NH];
  __shared__ float b1s[NH], b2s[NH], w3s[NH];
  int tid = threadIdx.x;
  int i0 = blockIdx.x * 64, j0 = blockIdx.y * 64;
#pragma unroll
  for (int it = 0; it < 16; ++it) {
    int idx = it * 256 + tid;
    int r = idx >> 6, c = idx & 63;
    Wt[c * 65 + r] = W[(size_t)(i0 + r) * OUT_U + j0 + c];  // read coalesced, write conflict-free
  }
  for (int v = tid; v < 64 * NH; v += 256) {
    As[v] = A[(size_t)i0 * NH + v];
    float s = 0.f;
#pragma unroll
    for (int kc = 0; kc < 8; ++kc) s += Bp[(size_t)kc * (OUT_U * NH) + (size_t)j0 * NH + v];
    Bs[v] = s;
  }
  if (tid < NH * NH) W2s[tid] = W2[tid];
  if (tid < NH) { b1s[tid] = b1[tid]; b2s[tid] = b2[tid]; w3s[tid] = W3[tid]; }
  __syncthreads();

  int lane = tid & 63, w = tid >> 6;
  float b3v = b3[0];
  float ar[NH];
#pragma unroll
  for (int h = 0; h < NH; ++h) ar[h] = As[lane * NH + h] + b1s[h];

#pragma unroll
  for (int g = 0; g < 4; ++g) {
    const int jb0 = w * 16 + g * 4;  // wave-uniform; g static after unroll
    float h1[4][NH], s2[4][NH];
#pragma unroll
    for (int u = 0; u < 4; ++u) {
#pragma unroll
      for (int p = 0; p < NH; p += 2) {
        float2 bp = *(const float2*)&Bs[(jb0 + u) * NH + p];  // uniform broadcast, 8B-aligned
        h1[u][p]     = fmaxf(ar[p] + bp.x, 0.f);
        h1[u][p + 1] = fmaxf(ar[p + 1] + bp.y, 0.f);
      }
    }
#pragma unroll
    for (int u = 0; u < 4; ++u)
#pragma unroll
      for (int q = 0; q < NH; ++q) s2[u][q] = b2s[q];
#pragma unroll
    for (int p = 0; p < NH; ++p) {
#pragma unroll
      for (int q = 0; q < NH; q += 2) {
        float2 wv2 = *(const float2*)&W2s[p * NH + q];  // uniform broadcast float2
#pragma unroll
        for (int u = 0; u < 4; ++u) {
          s2[u][q]     = fmaf(h1[u][p], wv2.x, s2[u][q]);
          s2[u][q + 1] = fmaf(h1[u][p], wv2.y, s2[u][q + 1]);
        }
      }
    }
#pragma unroll
    for (int u = 0; u < 4; ++u) {
      float d = b3v;
#pragma unroll
      for (int q = 0; q < NH; ++q) d = fmaf(fmaxf(s2[u][q], 0.f), w3s[q], d);
      float wn = Wt[(jb0 + u) * 65 + lane] + d;
      WnT[(size_t)(j0 + jb0 + u) * IN_U + i0 + lane] = (f16)wn;
    }
  }
}

// ================= k_gemm: logits = X16 @ WnT^T (UNCHANGED from R3/R4) ========
__device__ __forceinline__ void gld_lds16(const void* g, void* l) {
  __builtin_amdgcn_global_load_lds((const __attribute__((address_space(1))) uint32_t*)g,
                                   (__attribute__((address_space(3))) uint32_t*)l, 16, 0, 0);
}

__global__ __launch_bounds__(256) void k_gemm(const f16* __restrict__ Am,
                                              const f16* __restrict__ Bt,
                                              float* __restrict__ C) {
  constexpr int K = IN_U;    // 2048
  constexpr int N = OUT_U;   // 2048
  constexpr int BK = 64;
  constexpr int NKT = K / BK;  // 32
  __shared__ f16 Asl[128 * BK];
  __shared__ f16 Bsl[128 * BK];
  int tid = threadIdx.x;
  int lane = tid & 63;
  int w = tid >> 6;
  int wr = w >> 1, wc = w & 1;

  int orig = blockIdx.x;
  int swz = (orig & 7) * 64 + (orig >> 3);
  int bm = swz >> 4;
  int bn = swz & 15;

  int srow = lane >> 3;
  int schunk = (lane & 7) ^ srow;
  const f16* sA = Am + (size_t)(bm * 128 + w * 32 + srow) * K + schunk * 8;
  const f16* sB = Bt + (size_t)(bn * 128 + w * 32 + srow) * K + schunk * 8;
  f16* dA = Asl + w * 32 * BK;
  f16* dB = Bsl + w * 32 * BK;

  f32x16 acc[2][2];
#pragma unroll
  for (int mi = 0; mi < 2; ++mi)
#pragma unroll
    for (int ni = 0; ni < 2; ++ni) acc[mi][ni] = (f32x16)(0.f);

  int arow = wr * 64 + (lane & 31);
  int brow = wc * 64 + (lane & 31);
  int kgrp = lane >> 5;
  int rswz = lane & 7;

  for (int kt = 0; kt < NKT; ++kt) {
#pragma unroll
    for (int i = 0; i < 4; ++i) {
      gld_lds16(sA + (size_t)i * 8 * K, dA + i * 8 * BK);
      gld_lds16(sB + (size_t)i * 8 * K, dB + i * 8 * BK);
    }
    sA += BK; sB += BK;
    __syncthreads();

    f16x8 af[2][4], bf[2][4];
#pragma unroll
    for (int mi = 0; mi < 2; ++mi)
#pragma unroll
      for (int ks = 0; ks < 4; ++ks) {
        int pc = (ks * 2 + kgrp) ^ rswz;
        af[mi][ks] = *(const f16x8*)(Asl + (size_t)(arow + mi * 32) * BK + pc * 8);
        bf[mi][ks] = *(const f16x8*)(Bsl + (size_t)(brow + mi * 32) * BK + pc * 8);
      }
#pragma unroll
    for (int ks = 0; ks < 4; ++ks)
#pragma unroll
      for (int mi = 0; mi < 2; ++mi)
#pragma unroll
        for (int ni = 0; ni < 2; ++ni)
          acc[mi][ni] = __builtin_amdgcn_mfma_f32_32x32x16_f16(af[mi][ks], bf[ni][ks], acc[mi][ni], 0, 0, 0);
    __syncthreads();
  }

  int c0 = bn * 128 + wc * 64 + (lane & 31);
  int r0 = bm * 128 + wr * 64 + (lane >> 5) * 4;
#pragma unroll
  for (int mi = 0; mi < 2; ++mi)
#pragma unroll
    for (int ni = 0; ni < 2; ++ni)
#pragma unroll
      for (int v = 0; v < 16; ++v) {
        int row = r0 + mi * 32 + (v & 3) + 8 * (v >> 2);
        C[(size_t)row * N + c0 + ni * 32] = acc[mi][ni][v];
      }
}

// ================= k_softmax: row softmax in-place =================
__global__ __launch_bounds__(256) void k_softmax(float* __restrict__ L) {
  __shared__ float sred[4];
  int tid = threadIdx.x;
  int lane = tid & 63, w = tid >> 6;
  float4* Lr = (float4*)(L + (size_t)blockIdx.x * OUT_U);
  float4 v0 = Lr[tid];
  float4 v1 = Lr[tid + 256];
  float m = fmaxf(fmaxf(fmaxf(v0.x, v0.y), fmaxf(v0.z, v0.w)),
                  fmaxf(fmaxf(v1.x, v1.y), fmaxf(v1.z, v1.w)));
#pragma unroll
  for (int off = 32; off > 0; off >>= 1) m = fmaxf(m, __shfl_xor(m, off, 64));
  if (lane == 0) sred[w] = m;
  __syncthreads();
  m = fmaxf(fmaxf(sred[0], sred[1]), fmaxf(sred[2], sred[3]));
  __syncthreads();
  v0.x = __expf(v0.x - m); v0.y = __expf(v0.y - m);
  v0.z = __expf(v0.z - m); v0.w = __expf(v0.w - m);
  v1.x = __expf(v1.x - m); v1.y = __expf(v1.y - m);
  v1.z = __expf(v1.z - m); v1.w = __expf(v1.w - m);
  float s = v0.x + v0.y + v0.z + v0.w + v1.x + v1.y + v1.z + v1.w;
#pragma unroll
  for (int off = 32; off > 0; off >>= 1) s += __shfl_xor(s, off, 64);
  if (lane == 0) sred[w] = s;
  __syncthreads();
  s = sred[0] + sred[1] + sred[2] + sred[3];
  float inv = 1.f / s;
  v0.x *= inv; v0.y *= inv; v0.z *= inv; v0.w *= inv;
  v1.x *= inv; v1.y *= inv; v1.z *= inv; v1.w *= inv;
  Lr[tid] = v0;
  Lr[tid + 256] = v1;
}

extern "C" void kernel_launch(void* const* d_in, const int* in_sizes, int n_in,
                              void* d_out, int out_size, void* d_ws, size_t ws_size,
                              hipStream_t stream) {
  const float* X  = (const float*)d_in[0];
  const float* W  = (const float*)d_in[1];
  const float* W1 = (const float*)d_in[2];
  const float* b1 = (const float*)d_in[3];
  const float* W2 = (const float*)d_in[4];
  const float* b2 = (const float*)d_in[5];
  const float* W3 = (const float*)d_in[6];
  const float* b3 = (const float*)d_in[7];
  float* out = (float*)d_out;

  uint8_t* ws = (uint8_t*)d_ws;
  float* A   = (float*)ws;                      // 81,920 B
  float* Bp  = (float*)(ws + 81920);            // 655,360 B
  f16*   X16 = (f16*)(ws + 737280);             // 16,777,216 B
  f16*   WnT = (f16*)(ws + 737280 + 16777216);  // 8,388,608 B

  hipLaunchKernelGGL(k_prep, dim3(4864), dim3(256), 0, stream, W, W1, X, A, Bp, X16);
  hipLaunchKernelGGL(k_wnew, dim3(32, 32), dim3(256), 0, stream, W, A, Bp, b1, W2, b2, W3, b3, WnT);
  hipLaunchKernelGGL(k_gemm, dim3(512), dim3(256), 0, stream, X16, WnT, out);
  hipLaunchKernelGGL(k_softmax, dim3(4096), dim3(256), 0, stream, out);
}

// Round 7
// 204.948 us; speedup vs baseline: 1.1715x; 1.1156x over previous
//
#include <hip/hip_runtime.h>
#include <hip/hip_fp16.h>
#include <cstdint>

#define IN_U 2048
#define OUT_U 2048
#define NH 10
#define BATCH 4096

typedef _Float16 f16;
typedef _Float16 f16x8 __attribute__((ext_vector_type(8)));
typedef float f32x4 __attribute__((ext_vector_type(4)));
typedef float f32x16 __attribute__((ext_vector_type(16)));

// ================= k_prep: fused rowA | colB-partials | castX (UNCHANGED) =====
__global__ __launch_bounds__(256) void k_prep(const float* __restrict__ W,
                                              const float* __restrict__ W1,
                                              const float* __restrict__ X,
                                              float* __restrict__ A,
                                              float* __restrict__ Bp,
                                              f16* __restrict__ X16) {
  __shared__ float red[4 * 64 * NH];
  int blk = blockIdx.x;
  int tid = threadIdx.x;
  int lane = tid & 63;
  int wv = tid >> 6;

  if (blk < 512) {
    // ---- rowA: A[i][h] = sum_k W[i][k]*W1[k][h]; i = blk*4 + wv ----
    int i = blk * 4 + wv;
    float acc[NH];
#pragma unroll
    for (int h = 0; h < NH; ++h) acc[h] = 0.f;
    const float* wrow = W + (size_t)i * OUT_U;
    for (int k0 = lane * 4; k0 < OUT_U; k0 += 256) {
      float4 w4 = *(const float4*)(wrow + k0);
#pragma unroll
      for (int e = 0; e < 4; ++e) {
        float wval = (&w4.x)[e];
        const float2* w1p = (const float2*)(W1 + (size_t)(k0 + e) * NH);  // 8B-aligned (k*40)
        float2 p0 = w1p[0], p1 = w1p[1], p2 = w1p[2], p3 = w1p[3], p4 = w1p[4];
        acc[0] = fmaf(wval, p0.x, acc[0]); acc[1] = fmaf(wval, p0.y, acc[1]);
        acc[2] = fmaf(wval, p1.x, acc[2]); acc[3] = fmaf(wval, p1.y, acc[3]);
        acc[4] = fmaf(wval, p2.x, acc[4]); acc[5] = fmaf(wval, p2.y, acc[5]);
        acc[6] = fmaf(wval, p3.x, acc[6]); acc[7] = fmaf(wval, p3.y, acc[7]);
        acc[8] = fmaf(wval, p4.x, acc[8]); acc[9] = fmaf(wval, p4.y, acc[9]);
      }
    }
#pragma unroll
    for (int off = 32; off > 0; off >>= 1) {
#pragma unroll
      for (int h = 0; h < NH; ++h) acc[h] += __shfl_xor(acc[h], off, 64);
    }
    if (lane == 0) {
#pragma unroll
      for (int h = 0; h < NH; ++h) A[(size_t)i * NH + h] = acc[h];
    }
  } else if (blk < 768) {
    // ---- colB partial: Bp[kc][j][h] = sum_{k in chunk kc} W[k][j]*W1b[k][h] ----
    int pb = blk - 512;
    int jt = pb & 31, kc = pb >> 5;
    int j = jt * 64 + lane;
    float acc[NH];
#pragma unroll
    for (int h = 0; h < NH; ++h) acc[h] = 0.f;
    const float* w1b = W1 + (size_t)OUT_U * NH;
    int k0 = kc * 256 + wv * 64;
#pragma unroll 4
    for (int k = k0; k < k0 + 64; ++k) {
      float wval = W[(size_t)k * OUT_U + j];
      const float2* w1p = (const float2*)(w1b + (size_t)k * NH);
      float2 p0 = w1p[0], p1 = w1p[1], p2 = w1p[2], p3 = w1p[3], p4 = w1p[4];
      acc[0] = fmaf(wval, p0.x, acc[0]); acc[1] = fmaf(wval, p0.y, acc[1]);
      acc[2] = fmaf(wval, p1.x, acc[2]); acc[3] = fmaf(wval, p1.y, acc[3]);
      acc[4] = fmaf(wval, p2.x, acc[4]); acc[5] = fmaf(wval, p2.y, acc[5]);
      acc[6] = fmaf(wval, p3.x, acc[6]); acc[7] = fmaf(wval, p3.y, acc[7]);
      acc[8] = fmaf(wval, p4.x, acc[8]); acc[9] = fmaf(wval, p4.y, acc[9]);
    }
#pragma unroll
    for (int h = 0; h < NH; ++h) red[wv * 640 + lane * NH + h] = acc[h];
    __syncthreads();
    for (int v = tid; v < 640; v += 256) {
      float s = red[v] + red[640 + v] + red[1280 + v] + red[1920 + v];
      Bp[(size_t)kc * (OUT_U * NH) + jt * 640 + v] = s;
    }
  } else {
    // ---- castX ----
    int idx = (blk - 768) * 256 + tid;
    const float4* src = (const float4*)X;
    float4 a = src[idx * 2];
    float4 b = src[idx * 2 + 1];
    f16x8 o;
    o[0] = (f16)a.x; o[1] = (f16)a.y; o[2] = (f16)a.z; o[3] = (f16)a.w;
    o[4] = (f16)b.x; o[5] = (f16)b.y; o[6] = (f16)b.z; o[7] = (f16)b.w;
    *((f16x8*)X16 + idx) = o;
  }
}

// ================= k_wnew v4: W_new^T (f16) — spill-proof =================
// R4/R5 spilled (WRITE_SIZE 98/142MB vs 8.4MB output; VGPR 256/128).
// Fix: (a) MLP weights read as kernel-UNIFORM global scalars with static
// indices -> s_load -> SGPR (zero VGPR cost; v_fmac takes 1 SGPR operand);
// (b) s2 computed q-at-a-time so only h1 persists; (c) JB=2, arrays scoped
// inside loop. Live VGPRs ~45. No launch_bounds min-arg.
__global__ __launch_bounds__(256) void k_wnew(const float* __restrict__ W,
                                              const float* __restrict__ A,
                                              const float* __restrict__ Bp,
                                              const float* __restrict__ b1,
                                              const float* __restrict__ W2,
                                              const float* __restrict__ b2,
                                              const float* __restrict__ W3,
                                              const float* __restrict__ b3,
                                              f16* __restrict__ WnT) {
  __shared__ float Wt[64 * 65];
  __shared__ float As[64 * NH];
  __shared__ float Bs[64 * NH];
  int tid = threadIdx.x;
  int i0 = blockIdx.x * 64, j0 = blockIdx.y * 64;
#pragma unroll
  for (int it = 0; it < 16; ++it) {
    int idx = it * 256 + tid;
    int r = idx >> 6, c = idx & 63;
    Wt[c * 65 + r] = W[(size_t)(i0 + r) * OUT_U + j0 + c];  // coalesced read, conflict-free write
  }
  for (int v = tid; v < 64 * NH; v += 256) {
    As[v] = A[(size_t)i0 * NH + v];
    float s = 0.f;
#pragma unroll
    for (int kc = 0; kc < 8; ++kc) s += Bp[(size_t)kc * (OUT_U * NH) + (size_t)j0 * NH + v];
    Bs[v] = s;
  }
  __syncthreads();

  int lane = tid & 63, w = tid >> 6;
  float ar[NH];
#pragma unroll
  for (int h = 0; h < NH; ++h) ar[h] = As[lane * NH + h] + b1[h];  // b1[h]: uniform s_load

  for (int g = 0; g < 8; ++g) {   // 8 iterations x 2 j's; tiny live set per iter
    int jl = w * 16 + g * 2;      // wave-uniform local j
    float h1a[NH], h1b[NH];
#pragma unroll
    for (int p = 0; p < NH; ++p) {
      h1a[p] = fmaxf(ar[p] + Bs[jl * NH + p], 0.f);        // LDS broadcast
      h1b[p] = fmaxf(ar[p] + Bs[(jl + 1) * NH + p], 0.f);
    }
    float d0 = b3[0], d1 = b3[0];
#pragma unroll
    for (int q = 0; q < NH; ++q) {
      float sa = b2[q], sb = b2[q];                         // uniform s_load
#pragma unroll
      for (int p = 0; p < NH; ++p) {
        float w2 = W2[p * NH + q];                          // uniform s_load (SGPR)
        sa = fmaf(h1a[p], w2, sa);
        sb = fmaf(h1b[p], w2, sb);
      }
      float w3 = W3[q];                                     // uniform s_load
      d0 = fmaf(fmaxf(sa, 0.f), w3, d0);
      d1 = fmaf(fmaxf(sb, 0.f), w3, d1);
    }
    WnT[(size_t)(j0 + jl) * IN_U + i0 + lane]     = (f16)(Wt[jl * 65 + lane] + d0);
    WnT[(size_t)(j0 + jl + 1) * IN_U + i0 + lane] = (f16)(Wt[(jl + 1) * 65 + lane] + d1);
  }
}

// ================= k_gemm: logits = X16 @ WnT^T (UNCHANGED from R3/R4) ========
__device__ __forceinline__ void gld_lds16(const void* g, void* l) {
  __builtin_amdgcn_global_load_lds((const __attribute__((address_space(1))) uint32_t*)g,
                                   (__attribute__((address_space(3))) uint32_t*)l, 16, 0, 0);
}

__global__ __launch_bounds__(256) void k_gemm(const f16* __restrict__ Am,
                                              const f16* __restrict__ Bt,
                                              float* __restrict__ C) {
  constexpr int K = IN_U;    // 2048
  constexpr int N = OUT_U;   // 2048
  constexpr int BK = 64;
  constexpr int NKT = K / BK;  // 32
  __shared__ f16 Asl[128 * BK];
  __shared__ f16 Bsl[128 * BK];
  int tid = threadIdx.x;
  int lane = tid & 63;
  int w = tid >> 6;
  int wr = w >> 1, wc = w & 1;

  int orig = blockIdx.x;
  int swz = (orig & 7) * 64 + (orig >> 3);
  int bm = swz >> 4;
  int bn = swz & 15;

  int srow = lane >> 3;
  int schunk = (lane & 7) ^ srow;
  const f16* sA = Am + (size_t)(bm * 128 + w * 32 + srow) * K + schunk * 8;
  const f16* sB = Bt + (size_t)(bn * 128 + w * 32 + srow) * K + schunk * 8;
  f16* dA = Asl + w * 32 * BK;
  f16* dB = Bsl + w * 32 * BK;

  f32x16 acc[2][2];
#pragma unroll
  for (int mi = 0; mi < 2; ++mi)
#pragma unroll
    for (int ni = 0; ni < 2; ++ni) acc[mi][ni] = (f32x16)(0.f);

  int arow = wr * 64 + (lane & 31);
  int brow = wc * 64 + (lane & 31);
  int kgrp = lane >> 5;
  int rswz = lane & 7;

  for (int kt = 0; kt < NKT; ++kt) {
#pragma unroll
    for (int i = 0; i < 4; ++i) {
      gld_lds16(sA + (size_t)i * 8 * K, dA + i * 8 * BK);
      gld_lds16(sB + (size_t)i * 8 * K, dB + i * 8 * BK);
    }
    sA += BK; sB += BK;
    __syncthreads();

    f16x8 af[2][4], bf[2][4];
#pragma unroll
    for (int mi = 0; mi < 2; ++mi)
#pragma unroll
      for (int ks = 0; ks < 4; ++ks) {
        int pc = (ks * 2 + kgrp) ^ rswz;
        af[mi][ks] = *(const f16x8*)(Asl + (size_t)(arow + mi * 32) * BK + pc * 8);
        bf[mi][ks] = *(const f16x8*)(Bsl + (size_t)(brow + mi * 32) * BK + pc * 8);
      }
#pragma unroll
    for (int ks = 0; ks < 4; ++ks)
#pragma unroll
      for (int mi = 0; mi < 2; ++mi)
#pragma unroll
        for (int ni = 0; ni < 2; ++ni)
          acc[mi][ni] = __builtin_amdgcn_mfma_f32_32x32x16_f16(af[mi][ks], bf[ni][ks], acc[mi][ni], 0, 0, 0);
    __syncthreads();
  }

  int c0 = bn * 128 + wc * 64 + (lane & 31);
  int r0 = bm * 128 + wr * 64 + (lane >> 5) * 4;
#pragma unroll
  for (int mi = 0; mi < 2; ++mi)
#pragma unroll
    for (int ni = 0; ni < 2; ++ni)
#pragma unroll
      for (int v = 0; v < 16; ++v) {
        int row = r0 + mi * 32 + (v & 3) + 8 * (v >> 2);
        C[(size_t)row * N + c0 + ni * 32] = acc[mi][ni][v];
      }
}

// ================= k_softmax: row softmax in-place (UNCHANGED) =================
__global__ __launch_bounds__(256) void k_softmax(float* __restrict__ L) {
  __shared__ float sred[4];
  int tid = threadIdx.x;
  int lane = tid & 63, w = tid >> 6;
  float4* Lr = (float4*)(L + (size_t)blockIdx.x * OUT_U);
  float4 v0 = Lr[tid];
  float4 v1 = Lr[tid + 256];
  float m = fmaxf(fmaxf(fmaxf(v0.x, v0.y), fmaxf(v0.z, v0.w)),
                  fmaxf(fmaxf(v1.x, v1.y), fmaxf(v1.z, v1.w)));
#pragma unroll
  for (int off = 32; off > 0; off >>= 1) m = fmaxf(m, __shfl_xor(m, off, 64));
  if (lane == 0) sred[w] = m;
  __syncthreads();
  m = fmaxf(fmaxf(sred[0], sred[1]), fmaxf(sred[2], sred[3]));
  __syncthreads();
  v0.x = __expf(v0.x - m); v0.y = __expf(v0.y - m);
  v0.z = __expf(v0.z - m); v0.w = __expf(v0.w - m);
  v1.x = __expf(v1.x - m); v1.y = __expf(v1.y - m);
  v1.z = __expf(v1.z - m); v1.w = __expf(v1.w - m);
  float s = v0.x + v0.y + v0.z + v0.w + v1.x + v1.y + v1.z + v1.w;
#pragma unroll
  for (int off = 32; off > 0; off >>= 1) s += __shfl_xor(s, off, 64);
  if (lane == 0) sred[w] = s;
  __syncthreads();
  s = sred[0] + sred[1] + sred[2] + sred[3];
  float inv = 1.f / s;
  v0.x *= inv; v0.y *= inv; v0.z *= inv; v0.w *= inv;
  v1.x *= inv; v1.y *= inv; v1.z *= inv; v1.w *= inv;
  Lr[tid] = v0;
  Lr[tid + 256] = v1;
}

extern "C" void kernel_launch(void* const* d_in, const int* in_sizes, int n_in,
                              void* d_out, int out_size, void* d_ws, size_t ws_size,
                              hipStream_t stream) {
  const float* X  = (const float*)d_in[0];
  const float* W  = (const float*)d_in[1];
  const float* W1 = (const float*)d_in[2];
  const float* b1 = (const float*)d_in[3];
  const float* W2 = (const float*)d_in[4];
  const float* b2 = (const float*)d_in[5];
  const float* W3 = (const float*)d_in[6];
  const float* b3 = (const float*)d_in[7];
  float* out = (float*)d_out;

  uint8_t* ws = (uint8_t*)d_ws;
  float* A   = (float*)ws;                      // 81,920 B
  float* Bp  = (float*)(ws + 81920);            // 655,360 B
  f16*   X16 = (f16*)(ws + 737280);             // 16,777,216 B
  f16*   WnT = (f16*)(ws + 737280 + 16777216);  // 8,388,608 B

  hipLaunchKernelGGL(k_prep, dim3(4864), dim3(256), 0, stream, W, W1, X, A, Bp, X16);
  hipLaunchKernelGGL(k_wnew, dim3(32, 32), dim3(256), 0, stream, W, A, Bp, b1, W2, b2, W3, b3, WnT);
  hipLaunchKernelGGL(k_gemm, dim3(512), dim3(256), 0, stream, X16, WnT, out);
  hipLaunchKernelGGL(k_softmax, dim3(4096), dim3(256), 0, stream, out);
}

// Round 11
// 204.149 us; speedup vs baseline: 1.1761x; 1.0039x over previous
//
#include <hip/hip_runtime.h>
#include <hip/hip_fp16.h>
#include <cstdint>

#define IN_U 2048
#define OUT_U 2048
#define NH 10
#define BATCH 4096

typedef _Float16 f16;
typedef _Float16 f16x8 __attribute__((ext_vector_type(8)));
typedef float f32x4 __attribute__((ext_vector_type(4)));
typedef float f32x16 __attribute__((ext_vector_type(16)));

// ================= k_prep: fused rowA | colB-partials | castX (UNCHANGED) =====
__global__ __launch_bounds__(256) void k_prep(const float* __restrict__ W,
                                              const float* __restrict__ W1,
                                              const float* __restrict__ X,
                                              float* __restrict__ A,
                                              float* __restrict__ Bp,
                                              f16* __restrict__ X16) {
  __shared__ float red[4 * 64 * NH];
  int blk = blockIdx.x;
  int tid = threadIdx.x;
  int lane = tid & 63;
  int wv = tid >> 6;

  if (blk < 512) {
    // ---- rowA: A[i][h] = sum_k W[i][k]*W1[k][h]; i = blk*4 + wv ----
    int i = blk * 4 + wv;
    float acc[NH];
#pragma unroll
    for (int h = 0; h < NH; ++h) acc[h] = 0.f;
    const float* wrow = W + (size_t)i * OUT_U;
    for (int k0 = lane * 4; k0 < OUT_U; k0 += 256) {
      float4 w4 = *(const float4*)(wrow + k0);
#pragma unroll
      for (int e = 0; e < 4; ++e) {
        float wval = (&w4.x)[e];
        const float2* w1p = (const float2*)(W1 + (size_t)(k0 + e) * NH);  // 8B-aligned (k*40)
        float2 p0 = w1p[0], p1 = w1p[1], p2 = w1p[2], p3 = w1p[3], p4 = w1p[4];
        acc[0] = fmaf(wval, p0.x, acc[0]); acc[1] = fmaf(wval, p0.y, acc[1]);
        acc[2] = fmaf(wval, p1.x, acc[2]); acc[3] = fmaf(wval, p1.y, acc[3]);
        acc[4] = fmaf(wval, p2.x, acc[4]); acc[5] = fmaf(wval, p2.y, acc[5]);
        acc[6] = fmaf(wval, p3.x, acc[6]); acc[7] = fmaf(wval, p3.y, acc[7]);
        acc[8] = fmaf(wval, p4.x, acc[8]); acc[9] = fmaf(wval, p4.y, acc[9]);
      }
    }
#pragma unroll
    for (int off = 32; off > 0; off >>= 1) {
#pragma unroll
      for (int h = 0; h < NH; ++h) acc[h] += __shfl_xor(acc[h], off, 64);
    }
    if (lane == 0) {
#pragma unroll
      for (int h = 0; h < NH; ++h) A[(size_t)i * NH + h] = acc[h];
    }
  } else if (blk < 768) {
    // ---- colB partial: Bp[kc][j][h] = sum_{k in chunk kc} W[k][j]*W1b[k][h] ----
    int pb = blk - 512;
    int jt = pb & 31, kc = pb >> 5;
    int j = jt * 64 + lane;
    float acc[NH];
#pragma unroll
    for (int h = 0; h < NH; ++h) acc[h] = 0.f;
    const float* w1b = W1 + (size_t)OUT_U * NH;
    int k0 = kc * 256 + wv * 64;
#pragma unroll 4
    for (int k = k0; k < k0 + 64; ++k) {
      float wval = W[(size_t)k * OUT_U + j];
      const float2* w1p = (const float2*)(w1b + (size_t)k * NH);
      float2 p0 = w1p[0], p1 = w1p[1], p2 = w1p[2], p3 = w1p[3], p4 = w1p[4];
      acc[0] = fmaf(wval, p0.x, acc[0]); acc[1] = fmaf(wval, p0.y, acc[1]);
      acc[2] = fmaf(wval, p1.x, acc[2]); acc[3] = fmaf(wval, p1.y, acc[3]);
      acc[4] = fmaf(wval, p2.x, acc[4]); acc[5] = fmaf(wval, p2.y, acc[5]);
      acc[6] = fmaf(wval, p3.x, acc[6]); acc[7] = fmaf(wval, p3.y, acc[7]);
      acc[8] = fmaf(wval, p4.x, acc[8]); acc[9] = fmaf(wval, p4.y, acc[9]);
    }
#pragma unroll
    for (int h = 0; h < NH; ++h) red[wv * 640 + lane * NH + h] = acc[h];
    __syncthreads();
    for (int v = tid; v < 640; v += 256) {
      float s = red[v] + red[640 + v] + red[1280 + v] + red[1920 + v];
      Bp[(size_t)kc * (OUT_U * NH) + jt * 640 + v] = s;
    }
  } else {
    // ---- castX ----
    int idx = (blk - 768) * 256 + tid;
    const float4* src = (const float4*)X;
    float4 a = src[idx * 2];
    float4 b = src[idx * 2 + 1];
    f16x8 o;
    o[0] = (f16)a.x; o[1] = (f16)a.y; o[2] = (f16)a.z; o[3] = (f16)a.w;
    o[4] = (f16)b.x; o[5] = (f16)b.y; o[6] = (f16)b.z; o[7] = (f16)b.w;
    *((f16x8*)X16 + idx) = o;
  }
}

// ================= k_wnew v5: W_new^T (f16) — latency-oriented =================
// R7 (v4): no spill but 58.7us, VALUBusy 41%, occ 37% — per-thread 16 serial j's
// + uniform W2 loads re-issued every g-iter (runtime loop, not hoistable).
// v5: tile 64i x 16j (grid 32x128 = 4096 blocks -> occupancy-capped TLP);
// per-thread 2 g-iters; W2 in LDS (float2 broadcast); p-outer layer-2 with
// s2a/s2b accumulators (static indices); live ~70 VGPR.
__global__ __launch_bounds__(256) void k_wnew(const float* __restrict__ W,
                                              const float* __restrict__ A,
                                              const float* __restrict__ Bp,
                                              const float* __restrict__ b1,
                                              const float* __restrict__ W2,
                                              const float* __restrict__ b2,
                                              const float* __restrict__ W3,
                                              const float* __restrict__ b3,
                                              f16* __restrict__ WnT) {
  __shared__ float Wt[16 * 65];     // [c][r], c = local j (16), r = local i (64)
  __shared__ float As[64 * NH];
  __shared__ float Bs[16 * NH];
  __shared__ float W2s[NH * NH];
  int tid = threadIdx.x;
  int i0 = blockIdx.x * 64, j0 = blockIdx.y * 16;
#pragma unroll
  for (int it = 0; it < 4; ++it) {
    int idx = it * 256 + tid;
    int r = idx >> 4, c = idx & 15;
    Wt[c * 65 + r] = W[(size_t)(i0 + r) * OUT_U + j0 + c];  // 64B/16-lane segments
  }
  for (int v = tid; v < 64 * NH; v += 256) As[v] = A[(size_t)i0 * NH + v];
  if (tid < 16 * NH) {
    float s = 0.f;
#pragma unroll
    for (int kc = 0; kc < 8; ++kc) s += Bp[(size_t)kc * (OUT_U * NH) + (size_t)j0 * NH + tid];
    Bs[tid] = s;
  }
  if (tid < NH * NH) W2s[tid] = W2[tid];
  __syncthreads();

  int lane = tid & 63, w = tid >> 6;
  float ar[NH];
#pragma unroll
  for (int h = 0; h < NH; ++h) ar[h] = As[lane * NH + h] + b1[h];  // b1: uniform, hoisted

  for (int g = 0; g < 2; ++g) {
    int jl = w * 4 + g * 2;          // wave-uniform local j; wave w owns j's w*4..w*4+3
    float h1a[NH], h1b[NH];
#pragma unroll
    for (int p = 0; p < NH; ++p) {
      h1a[p] = fmaxf(ar[p] + Bs[jl * NH + p], 0.f);          // LDS broadcast
      h1b[p] = fmaxf(ar[p] + Bs[(jl + 1) * NH + p], 0.f);
    }
    float s2a[NH], s2b[NH];
#pragma unroll
    for (int q = 0; q < NH; ++q) { s2a[q] = b2[q]; s2b[q] = b2[q]; }
#pragma unroll
    for (int p = 0; p < NH; ++p) {
#pragma unroll
      for (int qq = 0; qq < NH; qq += 2) {
        float2 w2 = *(const float2*)&W2s[p * NH + qq];       // LDS broadcast float2
        s2a[qq]     = fmaf(h1a[p], w2.x, s2a[qq]);
        s2a[qq + 1] = fmaf(h1a[p], w2.y, s2a[qq + 1]);
        s2b[qq]     = fmaf(h1b[p], w2.x, s2b[qq]);
        s2b[qq + 1] = fmaf(h1b[p], w2.y, s2b[qq + 1]);
      }
    }
    float d0 = b3[0], d1 = b3[0];
#pragma unroll
    for (int q = 0; q < NH; ++q) {
      float w3 = W3[q];                                      // uniform, hoisted
      d0 = fmaf(fmaxf(s2a[q], 0.f), w3, d0);
      d1 = fmaf(fmaxf(s2b[q], 0.f), w3, d1);
    }
    WnT[(size_t)(j0 + jl) * IN_U + i0 + lane]     = (f16)(Wt[jl * 65 + lane] + d0);
    WnT[(size_t)(j0 + jl + 1) * IN_U + i0 + lane] = (f16)(Wt[(jl + 1) * 65 + lane] + d1);
  }
}

// ================= k_gemm: logits = X16 @ WnT^T (UNCHANGED from R3/R4) ========
__device__ __forceinline__ void gld_lds16(const void* g, void* l) {
  __builtin_amdgcn_global_load_lds((const __attribute__((address_space(1))) uint32_t*)g,
                                   (__attribute__((address_space(3))) uint32_t*)l, 16, 0, 0);
}

__global__ __launch_bounds__(256) void k_gemm(const f16* __restrict__ Am,
                                              const f16* __restrict__ Bt,
                                              float* __restrict__ C) {
  constexpr int K = IN_U;    // 2048
  constexpr int N = OUT_U;   // 2048
  constexpr int BK = 64;
  constexpr int NKT = K / BK;  // 32
  __shared__ f16 Asl[128 * BK];
  __shared__ f16 Bsl[128 * BK];
  int tid = threadIdx.x;
  int lane = tid & 63;
  int w = tid >> 6;
  int wr = w >> 1, wc = w & 1;

  int orig = blockIdx.x;
  int swz = (orig & 7) * 64 + (orig >> 3);
  int bm = swz >> 4;
  int bn = swz & 15;

  int srow = lane >> 3;
  int schunk = (lane & 7) ^ srow;
  const f16* sA = Am + (size_t)(bm * 128 + w * 32 + srow) * K + schunk * 8;
  const f16* sB = Bt + (size_t)(bn * 128 + w * 32 + srow) * K + schunk * 8;
  f16* dA = Asl + w * 32 * BK;
  f16* dB = Bsl + w * 32 * BK;

  f32x16 acc[2][2];
#pragma unroll
  for (int mi = 0; mi < 2; ++mi)
#pragma unroll
    for (int ni = 0; ni < 2; ++ni) acc[mi][ni] = (f32x16)(0.f);

  int arow = wr * 64 + (lane & 31);
  int brow = wc * 64 + (lane & 31);
  int kgrp = lane >> 5;
  int rswz = lane & 7;

  for (int kt = 0; kt < NKT; ++kt) {
#pragma unroll
    for (int i = 0; i < 4; ++i) {
      gld_lds16(sA + (size_t)i * 8 * K, dA + i * 8 * BK);
      gld_lds16(sB + (size_t)i * 8 * K, dB + i * 8 * BK);
    }
    sA += BK; sB += BK;
    __syncthreads();

    f16x8 af[2][4], bf[2][4];
#pragma unroll
    for (int mi = 0; mi < 2; ++mi)
#pragma unroll
      for (int ks = 0; ks < 4; ++ks) {
        int pc = (ks * 2 + kgrp) ^ rswz;
        af[mi][ks] = *(const f16x8*)(Asl + (size_t)(arow + mi * 32) * BK + pc * 8);
        bf[mi][ks] = *(const f16x8*)(Bsl + (size_t)(brow + mi * 32) * BK + pc * 8);
      }
#pragma unroll
    for (int ks = 0; ks < 4; ++ks)
#pragma unroll
      for (int mi = 0; mi < 2; ++mi)
#pragma unroll
        for (int ni = 0; ni < 2; ++ni)
          acc[mi][ni] = __builtin_amdgcn_mfma_f32_32x32x16_f16(af[mi][ks], bf[ni][ks], acc[mi][ni], 0, 0, 0);
    __syncthreads();
  }

  int c0 = bn * 128 + wc * 64 + (lane & 31);
  int r0 = bm * 128 + wr * 64 + (lane >> 5) * 4;
#pragma unroll
  for (int mi = 0; mi < 2; ++mi)
#pragma unroll
    for (int ni = 0; ni < 2; ++ni)
#pragma unroll
      for (int v = 0; v < 16; ++v) {
        int row = r0 + mi * 32 + (v & 3) + 8 * (v >> 2);
        C[(size_t)row * N + c0 + ni * 32] = acc[mi][ni][v];
      }
}

// ================= k_softmax: row softmax in-place (UNCHANGED) =================
__global__ __launch_bounds__(256) void k_softmax(float* __restrict__ L) {
  __shared__ float sred[4];
  int tid = threadIdx.x;
  int lane = tid & 63, w = tid >> 6;
  float4* Lr = (float4*)(L + (size_t)blockIdx.x * OUT_U);
  float4 v0 = Lr[tid];
  float4 v1 = Lr[tid + 256];
  float m = fmaxf(fmaxf(fmaxf(v0.x, v0.y), fmaxf(v0.z, v0.w)),
                  fmaxf(fmaxf(v1.x, v1.y), fmaxf(v1.z, v1.w)));
#pragma unroll
  for (int off = 32; off > 0; off >>= 1) m = fmaxf(m, __shfl_xor(m, off, 64));
  if (lane == 0) sred[w] = m;
  __syncthreads();
  m = fmaxf(fmaxf(sred[0], sred[1]), fmaxf(sred[2], sred[3]));
  __syncthreads();
  v0.x = __expf(v0.x - m); v0.y = __expf(v0.y - m);
  v0.z = __expf(v0.z - m); v0.w = __expf(v0.w - m);
  v1.x = __expf(v1.x - m); v1.y = __expf(v1.y - m);
  v1.z = __expf(v1.z - m); v1.w = __expf(v1.w - m);
  float s = v0.x + v0.y + v0.z + v0.w + v1.x + v1.y + v1.z + v1.w;
#pragma unroll
  for (int off = 32; off > 0; off >>= 1) s += __shfl_xor(s, off, 64);
  if (lane == 0) sred[w] = s;
  __syncthreads();
  s = sred[0] + sred[1] + sred[2] + sred[3];
  float inv = 1.f / s;
  v0.x *= inv; v0.y *= inv; v0.z *= inv; v0.w *= inv;
  v1.x *= inv; v1.y *= inv; v1.z *= inv; v1.w *= inv;
  Lr[tid] = v0;
  Lr[tid + 256] = v1;
}

extern "C" void kernel_launch(void* const* d_in, const int* in_sizes, int n_in,
                              void* d_out, int out_size, void* d_ws, size_t ws_size,
                              hipStream_t stream) {
  const float* X  = (const float*)d_in[0];
  const float* W  = (const float*)d_in[1];
  const float* W1 = (const float*)d_in[2];
  const float* b1 = (const float*)d_in[3];
  const float* W2 = (const float*)d_in[4];
  const float* b2 = (const float*)d_in[5];
  const float* W3 = (const float*)d_in[6];
  const float* b3 = (const float*)d_in[7];
  float* out = (float*)d_out;

  uint8_t* ws = (uint8_t*)d_ws;
  float* A   = (float*)ws;                      // 81,920 B
  float* Bp  = (float*)(ws + 81920);            // 655,360 B
  f16*   X16 = (f16*)(ws + 737280);             // 16,777,216 B
  f16*   WnT = (f16*)(ws + 737280 + 16777216);  // 8,388,608 B

  hipLaunchKernelGGL(k_prep, dim3(4864), dim3(256), 0, stream, W, W1, X, A, Bp, X16);
  hipLaunchKernelGGL(k_wnew, dim3(32, 128), dim3(256), 0, stream, W, A, Bp, b1, W2, b2, W3, b3, WnT);
  hipLaunchKernelGGL(k_gemm, dim3(512), dim3(256), 0, stream, X16, WnT, out);
  hipLaunchKernelGGL(k_softmax, dim3(4096), dim3(256), 0, stream, out);
}